// Round 3
// baseline (315.229 us; speedup 1.0000x reference)
//
#include <hip/hip_runtime.h>
#include <math.h>

#define BB 16
#define TT 2048
#define CC 1024
#define HH 64
#define MTOT (BB*TT)

typedef _Float16 f16;
typedef _Float16 f16x8 __attribute__((ext_vector_type(8)));
typedef float f32x4 __attribute__((ext_vector_type(4)));

// ws layout (f16 element offsets):
//   Wt [192][1024]   n-major transposed weights (q|k|v)
//   q  [32768][64]   row-major, pre-scaled by 1/8
//   k  [32768][64]   row-major
//   vT [80][32768]   h-major; row 64 = 1.0 (l-trick), rows 65-79 = 0
#define WT_OFF 0
#define Q_OFF  196608
#define K_OFF  (Q_OFF + (size_t)MTOT*HH)
#define VT_OFF (K_OFF + (size_t)MTOT*HH)

// ---------------- Kernel 0: W transpose + vT ones/zero rows ----------------
__global__ __launch_bounds__(256) void prep_kernel(
    const float* __restrict__ Wq, const float* __restrict__ Wk,
    const float* __restrict__ Wv, f16* __restrict__ ws)
{
    int e = blockIdx.x * 256 + threadIdx.x;   // 196608 + 16*32768 = 720896
    if (e < 196608) {
        int ng = e >> 10, k = e & 1023;
        int which = ng >> 6, n = ng & 63;
        const float* W = (which == 0) ? Wq : (which == 1) ? Wk : Wv;
        ws[WT_OFF + e] = (f16)W[k * HH + n];
    } else {
        int i = e - 196608;                   // 0 .. 524287
        int row = i >> 15;                    // 0..15 -> vT rows 64..79
        ws[VT_OFF + (size_t)(64 + row) * MTOT + (i & 32767)] =
            (row == 0) ? (f16)1.0f : (f16)0.0f;
    }
}

__device__ inline f16x8 cvt8(float4 u, float4 v) {
    f16x8 r;
    r[0] = (f16)u.x; r[1] = (f16)u.y; r[2] = (f16)u.z; r[3] = (f16)u.w;
    r[4] = (f16)v.x; r[5] = (f16)v.y; r[6] = (f16)v.z; r[7] = (f16)v.w;
    return r;
}

// ---------------- Kernel 1: QKV projection, no-LDS MFMA ----------------
// 256 blocks x 256 thr; wave w owns 2 m-tiles (rows m0+w*32 .. +31), all 12
// n-tiles (q|k|v). A from x (fp32->f16, reg double-buffer), B from Wt
// (global; same addrs for all 4 waves -> L1 broadcast).
__global__ __launch_bounds__(256, 2) void qkv_kernel(
    const float* __restrict__ x,
    const float* __restrict__ bq, const float* __restrict__ bk,
    const float* __restrict__ bv, f16* __restrict__ ws)
{
    __shared__ f16 Vt[HH][136];    // v^T staging (epilogue only)

    const f16* wt = ws + WT_OFF;
    const int tid  = threadIdx.x;
    const int lane = tid & 63, w = tid >> 6;
    const int c = lane & 15, g = lane >> 4;
    const int m0 = blockIdx.x * 128;
    const int mw = m0 + w * 32;

    const float* xr0 = x + (size_t)(mw + c) * CC;        // mt=0 row
    const float* xr1 = x + (size_t)(mw + 16 + c) * CC;   // mt=1 row

    f32x4 acc[2][12];
    #pragma unroll
    for (int mt = 0; mt < 2; ++mt)
        #pragma unroll
        for (int nt = 0; nt < 12; ++nt) acc[mt][nt] = (f32x4){0.f, 0.f, 0.f, 0.f};

    // prologue: load ks=0 A operands
    float4 a00 = *(const float4*)(xr0 + g * 8);
    float4 a01 = *(const float4*)(xr0 + g * 8 + 4);
    float4 a10 = *(const float4*)(xr1 + g * 8);
    float4 a11 = *(const float4*)(xr1 + g * 8 + 4);

    for (int ks = 0; ks < 32; ++ks) {
        float4 n00, n01, n10, n11;
        if (ks < 31) {
            int k = (ks + 1) * 32 + g * 8;
            n00 = *(const float4*)(xr0 + k);
            n01 = *(const float4*)(xr0 + k + 4);
            n10 = *(const float4*)(xr1 + k);
            n11 = *(const float4*)(xr1 + k + 4);
        }
        f16x8 bf[12];
        #pragma unroll
        for (int nt = 0; nt < 12; ++nt)
            bf[nt] = *(const f16x8*)(wt + (size_t)(nt * 16 + c) * CC + ks * 32 + g * 8);
        f16x8 af0 = cvt8(a00, a01);
        f16x8 af1 = cvt8(a10, a11);
        #pragma unroll
        for (int nt = 0; nt < 12; ++nt) {
            acc[0][nt] = __builtin_amdgcn_mfma_f32_16x16x32_f16(af0, bf[nt], acc[0][nt], 0, 0, 0);
            acc[1][nt] = __builtin_amdgcn_mfma_f32_16x16x32_f16(af1, bf[nt], acc[1][nt], 0, 0, 0);
        }
        a00 = n00; a01 = n01; a10 = n10; a11 = n11;
    }

    // epilogue: C/D row (in 16-tile) = 4g+r, col = nt*16+c
    #pragma unroll
    for (int mt = 0; mt < 2; ++mt) {
        #pragma unroll
        for (int nt = 0; nt < 4; ++nt) {         // q (scale 1/8 folded)
            int h = nt * 16 + c;
            float bias = bq[h];
            #pragma unroll
            for (int r = 0; r < 4; ++r) {
                int m = mw + mt * 16 + 4 * g + r;
                ws[Q_OFF + (size_t)m * HH + h] = (f16)((acc[mt][nt][r] + bias) * 0.125f);
            }
        }
        #pragma unroll
        for (int nt = 4; nt < 8; ++nt) {         // k
            int h = (nt - 4) * 16 + c;
            float bias = bk[h];
            #pragma unroll
            for (int r = 0; r < 4; ++r) {
                int m = mw + mt * 16 + 4 * g + r;
                ws[K_OFF + (size_t)m * HH + h] = (f16)(acc[mt][nt][r] + bias);
            }
        }
        #pragma unroll
        for (int nt = 8; nt < 12; ++nt) {        // v -> LDS transpose
            int h = (nt - 8) * 16 + c;
            float bias = bv[h];
            #pragma unroll
            for (int r = 0; r < 4; ++r)
                Vt[h][w * 32 + mt * 16 + 4 * g + r] = (f16)(acc[mt][nt][r] + bias);
        }
    }
    __syncthreads();
    {   // coalesced vT write: thread t -> row h=t>>2, 32-col segment (t&3)
        int h = tid >> 2, seg = tid & 3;
        f16* dst = ws + VT_OFF + (size_t)h * MTOT + m0 + seg * 32;
        #pragma unroll
        for (int j = 0; j < 4; ++j)
            *(f16x8*)(dst + j * 8) = *(f16x8*)&Vt[h][seg * 32 + j * 8];
    }
}

// ---------------- Kernel 2: causal flash attention, barrier-free ----------------
// 512 blocks x 256 thr. Wave w covers ALL 64 q-rows (4 m-tiles) and s-tiles
// st = w, w+4, ... (no max-subtraction -> partials combine by plain sum).
// l via ones-column V tile (nt=4). Only LDS: wave-private P + epilogue Obuf.
__global__ __launch_bounds__(256, 2) void attn_kernel(
    const f16* __restrict__ ws, float* __restrict__ out)
{
    const f16* qp = ws + Q_OFF;
    const f16* kp = ws + K_OFF;
    const f16* vt = ws + VT_OFF;

    __shared__ f16  Ps[4][16][72];     // per-wave P round-trip (9216 B)
    __shared__ float Obuf[64][68];     // combine buffer (17408 B)

    const int tid  = threadIdx.x;
    const int lane = tid & 63, w = tid >> 6;
    const int c = lane & 15, g = lane >> 4;

    // swizzle: XCD r gets batches 2r,2r+1; blocks i,i+256 complementary tiles
    const int id = blockIdx.x;
    const int r8 = id & 7, j = id >> 3;
    const int half = j >> 5, qr = j & 31;
    const int b  = 2 * r8 + half;
    const int qi = half ? (31 - qr) : qr;
    const int q0 = qi * 64;
    const size_t rowbase = (size_t)b * TT;

    // zero Obuf (done strictly before post-loop barrier)
    for (int i = tid; i < 64 * 68; i += 256) ((float*)Obuf)[i] = 0.f;

    // Q fragments hoisted for whole kernel: aq[mt][chunk]
    f16x8 aq[4][2];
    #pragma unroll
    for (int mt = 0; mt < 4; ++mt) {
        const f16* qrow = qp + (rowbase + q0 + mt * 16 + c) * HH;
        aq[mt][0] = *(const f16x8*)(qrow + g * 8);
        aq[mt][1] = *(const f16x8*)(qrow + 32 + g * 8);
    }

    f32x4 o[4][5];
    #pragma unroll
    for (int mt = 0; mt < 4; ++mt)
        #pragma unroll
        for (int nt = 0; nt < 5; ++nt) o[mt][nt] = (f32x4){0.f, 0.f, 0.f, 0.f};

    for (int st = w; st <= qi; st += 4) {
        const int s0 = st * 64;
        // K fragments: B[k=h][n=s]
        f16x8 bk_[4][2];
        #pragma unroll
        for (int nt = 0; nt < 4; ++nt) {
            const f16* krow = kp + (rowbase + s0 + nt * 16 + c) * HH;
            bk_[nt][0] = *(const f16x8*)(krow + g * 8);
            bk_[nt][1] = *(const f16x8*)(krow + 32 + g * 8);
        }
        // V fragments: B[k=s][n=h]; nt=4 is the ones/zeros l-tile
        f16x8 bv_[5][2];
        #pragma unroll
        for (int nt = 0; nt < 5; ++nt) {
            const f16* vrow = vt + (size_t)(nt * 16 + c) * MTOT + rowbase + s0;
            bv_[nt][0] = *(const f16x8*)(vrow + g * 8);
            bv_[nt][1] = *(const f16x8*)(vrow + 32 + g * 8);
        }

        #pragma unroll
        for (int mt = 0; mt < 4; ++mt) {
            f32x4 s[4];
            #pragma unroll
            for (int nt = 0; nt < 4; ++nt) {
                s[nt] = (f32x4){0.f, 0.f, 0.f, 0.f};
                s[nt] = __builtin_amdgcn_mfma_f32_16x16x32_f16(aq[mt][0], bk_[nt][0], s[nt], 0, 0, 0);
                s[nt] = __builtin_amdgcn_mfma_f32_16x16x32_f16(aq[mt][1], bk_[nt][1], s[nt], 0, 0, 0);
            }
            if (st == qi) {   // diagonal tile: causal mask
                #pragma unroll
                for (int nt = 0; nt < 4; ++nt)
                    #pragma unroll
                    for (int rr = 0; rr < 4; ++rr)
                        if (nt * 16 + c > mt * 16 + 4 * g + rr) s[nt][rr] = -INFINITY;
            }
            // P = exp(S) (no max: scores bounded); f16 -> wave-private LDS
            #pragma unroll
            for (int nt = 0; nt < 4; ++nt)
                #pragma unroll
                for (int rr = 0; rr < 4; ++rr)
                    Ps[w][4 * g + rr][nt * 16 + c] = (f16)__expf(s[nt][rr]);
            // in-wave RAW on Ps: hardware/compiler order via lgkmcnt, no barrier
            f16x8 pa0 = *(f16x8*)&Ps[w][c][g * 8];
            f16x8 pa1 = *(f16x8*)&Ps[w][c][32 + g * 8];
            #pragma unroll
            for (int nt = 0; nt < 5; ++nt) {
                o[mt][nt] = __builtin_amdgcn_mfma_f32_16x16x32_f16(pa0, bv_[nt][0], o[mt][nt], 0, 0, 0);
                o[mt][nt] = __builtin_amdgcn_mfma_f32_16x16x32_f16(pa1, bv_[nt][1], o[mt][nt], 0, 0, 0);
            }
        }
    }

    __syncthreads();   // zeroing done + all waves' loops done
    #pragma unroll
    for (int mt = 0; mt < 4; ++mt) {
        #pragma unroll
        for (int nt = 0; nt < 4; ++nt)
            #pragma unroll
            for (int rr = 0; rr < 4; ++rr)
                atomicAdd(&Obuf[mt * 16 + 4 * g + rr][nt * 16 + c], o[mt][nt][rr]);
        if (c == 0)
            #pragma unroll
            for (int rr = 0; rr < 4; ++rr)
                atomicAdd(&Obuf[mt * 16 + 4 * g + rr][64], o[mt][4][rr]);   // l
    }
    __syncthreads();

    {   // normalize + coalesced float4 store
        int row = tid >> 2, seg = tid & 3;
        float inv = 1.0f / Obuf[row][64];
        float* dst = out + (rowbase + q0 + row) * HH + seg * 16;
        #pragma unroll
        for (int k = 0; k < 4; ++k) {
            float4 v = *(float4*)&Obuf[row][seg * 16 + k * 4];
            v.x *= inv; v.y *= inv; v.z *= inv; v.w *= inv;
            *(float4*)(dst + k * 4) = v;
        }
    }
}

extern "C" void kernel_launch(void* const* d_in, const int* in_sizes, int n_in,
                              void* d_out, int out_size, void* d_ws, size_t ws_size,
                              hipStream_t stream) {
    const float* x  = (const float*)d_in[0];
    const float* Wq = (const float*)d_in[1];
    const float* bq = (const float*)d_in[2];
    const float* Wk = (const float*)d_in[3];
    const float* bk = (const float*)d_in[4];
    const float* Wv = (const float*)d_in[5];
    const float* bv = (const float*)d_in[6];
    f16*   ws  = (f16*)d_ws;
    float* out = (float*)d_out;

    prep_kernel<<<2816, 256, 0, stream>>>(Wq, Wk, Wv, ws);
    qkv_kernel<<<MTOT / 128, 256, 0, stream>>>(x, bq, bk, bv, ws);
    attn_kernel<<<512, 256, 0, stream>>>(ws, out);
}

// Round 4
// 241.029 us; speedup vs baseline: 1.3078x; 1.3078x over previous
//
#include <hip/hip_runtime.h>
#include <math.h>

#define BB 16
#define TT 2048
#define CC 1024
#define HH 64
#define MTOT (BB*TT)

typedef _Float16 f16;
typedef _Float16 f16x8 __attribute__((ext_vector_type(8)));
typedef float f32x4 __attribute__((ext_vector_type(4)));

// ws layout (f16 element offsets):
//   Wt [192][1024]   n-major transposed weights (q|k|v)
//   q  [32768][64]   row-major, pre-scaled by 1/8
//   k  [32768][64]   row-major
//   vT [64][32768]   h-major transposed v
#define WT_OFF 0
#define Q_OFF  196608
#define K_OFF  (Q_OFF + (size_t)MTOT*HH)
#define VT_OFF (K_OFF + (size_t)MTOT*HH)

__device__ __forceinline__ void async16(const void* g, void* l) {
    __builtin_amdgcn_global_load_lds(
        (const __attribute__((address_space(1))) unsigned int*)g,
        (__attribute__((address_space(3))) unsigned int*)l, 16, 0, 0);
}

__device__ __forceinline__ f16x8 cvt8(float4 u, float4 v) {
    f16x8 r;
    r[0] = (f16)u.x; r[1] = (f16)u.y; r[2] = (f16)u.z; r[3] = (f16)u.w;
    r[4] = (f16)v.x; r[5] = (f16)v.y; r[6] = (f16)v.z; r[7] = (f16)v.w;
    return r;
}

// ---------------- Kernel 0: W transpose + convert ----------------
__global__ __launch_bounds__(256) void prep_kernel(
    const float* __restrict__ Wq, const float* __restrict__ Wk,
    const float* __restrict__ Wv, f16* __restrict__ ws)
{
    int e = blockIdx.x * 256 + threadIdx.x;      // 196608 elems
    int ng = e >> 10, k = e & 1023;
    int which = ng >> 6, n = ng & 63;
    const float* W = (which == 0) ? Wq : (which == 1) ? Wk : Wv;
    ws[WT_OFF + e] = (f16)W[k * HH + n];
}

// ---------------- Kernel 1: QKV projection (MFMA, global_load_lds) ----------------
// BM=64, N=192, BK=64. 512 blocks x 4 waves. Wave w: n-tiles {3w..3w+2},
// all 4 m-tiles. Xs fp32 / Ws f16 staged via global_load_lds with XOR
// granule swizzle (no padding allowed): 2-way bank aliasing = free.
__global__ __launch_bounds__(256, 2) void qkv_kernel(
    const float* __restrict__ x,
    const float* __restrict__ bq, const float* __restrict__ bk,
    const float* __restrict__ bv, f16* __restrict__ ws)
{
    __shared__ __align__(16) float Xs[64 * 64];   // 16 KB, granule-swizzled
    __shared__ __align__(16) f16   Ws[192 * 64];  // 24 KB, granule-swizzled
    __shared__ __align__(16) f16   Vt[64][72];    //  9 KB epilogue transpose

    const f16* wt = ws + WT_OFF;
    const int tid  = threadIdx.x;
    const int lane = tid & 63, w = tid >> 6;
    const int c = lane & 15, g = lane >> 4;
    const int m0 = blockIdx.x * 64;

    f32x4 acc[4][3];     // [mt][j]
    #pragma unroll
    for (int mt = 0; mt < 4; ++mt)
        #pragma unroll
        for (int j = 0; j < 3; ++j) acc[mt][j] = (f32x4){0.f, 0.f, 0.f, 0.f};

    for (int k0 = 0; k0 < CC; k0 += 64) {
        __syncthreads();   // previous iteration's fragment reads done
        // stage X tile (64x64 fp32): 1024 granules, 4 calls/wave
        #pragma unroll
        for (int i = 0; i < 4; ++i) {
            int G0 = (w * 4 + i) * 64;
            int G = G0 + lane;
            int r = G >> 4, q = G & 15;
            async16(x + (size_t)(m0 + r) * CC + k0 + ((q ^ (r & 15)) << 2),
                    Xs + G0 * 4);
        }
        // stage W tile (192x64 f16): 1536 granules, 6 calls/wave
        #pragma unroll
        for (int i = 0; i < 6; ++i) {
            int G0 = (w * 6 + i) * 64;
            int G = G0 + lane;
            int r = G >> 3, q = G & 7;
            async16(wt + (size_t)r * CC + k0 + ((q ^ (r & 7)) << 3),
                    Ws + G0 * 8);
        }
        __syncthreads();   // vmcnt drain: staged data visible

        #pragma unroll
        for (int kk = 0; kk < 2; ++kk) {
            f16x8 bfr[3];
            #pragma unroll
            for (int j = 0; j < 3; ++j) {
                int r = (3 * w + j) * 16 + c;
                int p = (kk * 4 + g) ^ (c & 7);
                bfr[j] = *(const f16x8*)(Ws + r * 64 + p * 8);
            }
            #pragma unroll
            for (int mt = 0; mt < 4; ++mt) {
                int r = mt * 16 + c;
                int q = kk * 8 + 2 * g;
                float4 f0 = *(const float4*)(Xs + r * 64 + (q ^ c) * 4);
                float4 f1 = *(const float4*)(Xs + r * 64 + ((q + 1) ^ c) * 4);
                f16x8 a = cvt8(f0, f1);
                #pragma unroll
                for (int j = 0; j < 3; ++j)
                    acc[mt][j] = __builtin_amdgcn_mfma_f32_16x16x32_f16(
                        a, bfr[j], acc[mt][j], 0, 0, 0);
            }
        }
    }

    // epilogue: C/D row = 4g+r (in 16-tile), col = nt*16+c
    #pragma unroll
    for (int j = 0; j < 3; ++j) {
        int nt = 3 * w + j;
        int plane = nt >> 2;             // 0=q 1=k 2=v
        int h = (nt & 3) * 16 + c;
        if (plane == 0) {
            float bias = bq[h];
            #pragma unroll
            for (int mt = 0; mt < 4; ++mt)
                #pragma unroll
                for (int r = 0; r < 4; ++r) {
                    int m = m0 + mt * 16 + 4 * g + r;
                    ws[Q_OFF + (size_t)m * HH + h] =
                        (f16)((acc[mt][j][r] + bias) * 0.125f);
                }
        } else if (plane == 1) {
            float bias = bk[h];
            #pragma unroll
            for (int mt = 0; mt < 4; ++mt)
                #pragma unroll
                for (int r = 0; r < 4; ++r) {
                    int m = m0 + mt * 16 + 4 * g + r;
                    ws[K_OFF + (size_t)m * HH + h] = (f16)(acc[mt][j][r] + bias);
                }
        } else {
            float bias = bv[h];
            #pragma unroll
            for (int mt = 0; mt < 4; ++mt)
                #pragma unroll
                for (int r = 0; r < 4; ++r)
                    Vt[h][mt * 16 + 4 * g + r] = (f16)(acc[mt][j][r] + bias);
        }
    }
    __syncthreads();
    {   // coalesced vT write: thread t -> row h=t>>2, 16-col segment t&3
        int h = tid >> 2, seg = tid & 3;
        f16* dst = ws + VT_OFF + (size_t)h * MTOT + m0 + seg * 16;
        *(f16x8*)dst       = *(f16x8*)&Vt[h][seg * 16];
        *(f16x8*)(dst + 8) = *(f16x8*)&Vt[h][seg * 16 + 8];
    }
}

// ---------------- Kernel 2: causal flash attention ----------------
// 512 blocks x 4 waves; wave w exclusively owns q-rows [16w,16w+16) of the
// 64-row Q tile -> no cross-wave combine. K/V staged in LDS (shared), exp-only
// softmax (scores bounded), l via constant ones-column B fragment.
__global__ __launch_bounds__(256, 2) void attn_kernel(
    const f16* __restrict__ ws, float* __restrict__ out)
{
    const f16* qp = ws + Q_OFF;
    const f16* kp = ws + K_OFF;
    const f16* vt = ws + VT_OFF;

    __shared__ __align__(16) f16 Qs[64 * 64];     // 8 KB, granule-swizzled
    __shared__ __align__(16) f16 Ks[64 * 64];
    __shared__ __align__(16) f16 Vs[64 * 64];
    __shared__ __align__(16) f16 Ps[4][16][72];   // wave-private P round-trip

    const int tid  = threadIdx.x;
    const int lane = tid & 63, w = tid >> 6;
    const int c = lane & 15, g = lane >> 4;

    // swizzle: XCD r8 gets batches 2r8,2r8+1; blocks i,i+256 complementary
    const int id = blockIdx.x;
    const int r8 = id & 7, j = id >> 3;
    const int half = j >> 5, qr = j & 31;
    const int b  = 2 * r8 + half;
    const int qi = half ? (31 - qr) : qr;
    const int q0 = qi * 64;
    const size_t rowbase = (size_t)b * TT;

    // stage Q (64x64 f16): 512 granules, 2 calls/wave
    #pragma unroll
    for (int i = 0; i < 2; ++i) {
        int G0 = (w * 2 + i) * 64;
        int G = G0 + lane;
        int r = G >> 3, q = G & 7;
        async16(qp + (rowbase + q0 + r) * HH + ((q ^ (r & 7)) << 3),
                Qs + G0 * 8);
    }

    f32x4 o[5];   // 4 output n-tiles + ones-column (row-sum l)
    #pragma unroll
    for (int nt = 0; nt < 5; ++nt) o[nt] = (f32x4){0.f, 0.f, 0.f, 0.f};

    f16x8 onesf;
    #pragma unroll
    for (int i = 0; i < 8; ++i) onesf[i] = (c == 0) ? (f16)1.0f : (f16)0.0f;

    for (int st = 0; st <= qi; ++st) {
        const int s0 = st * 64;
        __syncthreads();   // prev tile's fragment reads done (also Q guard)
        #pragma unroll
        for (int i = 0; i < 2; ++i) {
            int G0 = (w * 2 + i) * 64;
            int G = G0 + lane;
            int r = G >> 3, q = G & 7;
            int sw = (q ^ (r & 7)) << 3;
            async16(kp + (rowbase + s0 + r) * HH + sw, Ks + G0 * 8);
            async16(vt + (size_t)r * MTOT + rowbase + s0 + sw, Vs + G0 * 8);
        }
        __syncthreads();   // staged data visible

        // Q A-fragments (2 ds_read_b128)
        f16x8 aq[2];
        {
            int r = w * 16 + c;
            aq[0] = *(const f16x8*)(Qs + r * 64 + ((g)     ^ (c & 7)) * 8);
            aq[1] = *(const f16x8*)(Qs + r * 64 + ((4 + g) ^ (c & 7)) * 8);
        }

        // S = Q K^T : 8 mfma
        f32x4 s[4];
        #pragma unroll
        for (int nt = 0; nt < 4; ++nt) {
            s[nt] = (f32x4){0.f, 0.f, 0.f, 0.f};
            int r = nt * 16 + c;
            f16x8 b0 = *(const f16x8*)(Ks + r * 64 + ((g)     ^ (c & 7)) * 8);
            f16x8 b1 = *(const f16x8*)(Ks + r * 64 + ((4 + g) ^ (c & 7)) * 8);
            s[nt] = __builtin_amdgcn_mfma_f32_16x16x32_f16(aq[0], b0, s[nt], 0, 0, 0);
            s[nt] = __builtin_amdgcn_mfma_f32_16x16x32_f16(aq[1], b1, s[nt], 0, 0, 0);
        }

        if (st == qi) {   // diagonal tile: causal mask
            #pragma unroll
            for (int nt = 0; nt < 4; ++nt)
                #pragma unroll
                for (int rr = 0; rr < 4; ++rr)
                    if (nt * 16 + c > w * 16 + 4 * g + rr) s[nt][rr] = -INFINITY;
        }

        // P = exp(S) (no max: scores bounded) -> wave-private LDS
        #pragma unroll
        for (int nt = 0; nt < 4; ++nt)
            #pragma unroll
            for (int rr = 0; rr < 4; ++rr)
                Ps[w][4 * g + rr][nt * 16 + c] = (f16)__expf(s[nt][rr]);
        // in-wave RAW on Ps: compiler orders via lgkmcnt, no barrier needed
        f16x8 pa0 = *(f16x8*)&Ps[w][c][g * 8];
        f16x8 pa1 = *(f16x8*)&Ps[w][c][32 + g * 8];

        // O += P V (+ ones column for l): 10 mfma
        #pragma unroll
        for (int nt = 0; nt < 4; ++nt) {
            int r = nt * 16 + c;
            f16x8 v0 = *(const f16x8*)(Vs + r * 64 + ((g)     ^ (c & 7)) * 8);
            f16x8 v1 = *(const f16x8*)(Vs + r * 64 + ((4 + g) ^ (c & 7)) * 8);
            o[nt] = __builtin_amdgcn_mfma_f32_16x16x32_f16(pa0, v0, o[nt], 0, 0, 0);
            o[nt] = __builtin_amdgcn_mfma_f32_16x16x32_f16(pa1, v1, o[nt], 0, 0, 0);
        }
        o[4] = __builtin_amdgcn_mfma_f32_16x16x32_f16(pa0, onesf, o[4], 0, 0, 0);
        o[4] = __builtin_amdgcn_mfma_f32_16x16x32_f16(pa1, onesf, o[4], 0, 0, 0);
    }

    // epilogue: l sits at col 0 of each 16-lane group -> broadcast, normalize
    #pragma unroll
    for (int rr = 0; rr < 4; ++rr) {
        float lv = __shfl(o[4][rr], lane & 48);
        float inv = 1.0f / lv;
        int mrow = q0 + w * 16 + 4 * g + rr;
        #pragma unroll
        for (int nt = 0; nt < 4; ++nt)
            out[(rowbase + mrow) * HH + nt * 16 + c] = o[nt][rr] * inv;
    }
}

extern "C" void kernel_launch(void* const* d_in, const int* in_sizes, int n_in,
                              void* d_out, int out_size, void* d_ws, size_t ws_size,
                              hipStream_t stream) {
    const float* x  = (const float*)d_in[0];
    const float* Wq = (const float*)d_in[1];
    const float* bq = (const float*)d_in[2];
    const float* Wk = (const float*)d_in[3];
    const float* bk = (const float*)d_in[4];
    const float* Wv = (const float*)d_in[5];
    const float* bv = (const float*)d_in[6];
    f16*   ws  = (f16*)d_ws;
    float* out = (float*)d_out;

    prep_kernel<<<768, 256, 0, stream>>>(Wq, Wk, Wv, ws);
    qkv_kernel<<<MTOT / 64, 256, 0, stream>>>(x, bq, bk, bv, ws);
    dim3 g2(512);
    attn_kernel<<<g2, 256, 0, stream>>>(ws, out);
}